// Round 1
// baseline (204.032 us; speedup 1.0000x reference)
//
#include <hip/hip_runtime.h>

// Problem shape (fixed by setup_inputs): x = (B=8, H=512, W=512, C=64) fp32, NHWC.
// Outputs: ll, lh, hl, hh each (8, 256, 256, 64) fp32, concatenated in d_out.

#define B_    8
#define H_    512
#define W_    512
#define C_    64
#define HO_   (H_ / 2)
#define WO_   (W_ / 2)
#define CV_   (C_ / 4)                       // float4 chunks per pixel = 16
#define ROWV_ (W_ * CV_)                     // input row stride in float4 = 8192
#define SUBV_ (B_ * HO_ * WO_ * CV_)         // one subband, in float4 = 8388608

__global__ __launch_bounds__(256) void WaveLetPooling_38843684225881_kernel(
    const float4* __restrict__ x, float4* __restrict__ out, int total)
{
    int idx = blockIdx.x * blockDim.x + threadIdx.x;
    if (idx >= total) return;

    // idx = ((b*HO + h)*WO + w)*CV + cv   (CV=16, WO=256, HO=256 are powers of 2)
    const int cv = idx & (CV_ - 1);
    const int w  = (idx >> 4) & (WO_ - 1);
    const int h  = (idx >> 12) & (HO_ - 1);
    const int b  = idx >> 20;

    // input float4 index of (b, 2h, 2w, 4*cv)
    const int in_idx = ((b * H_ + 2 * h) * W_ + 2 * w) * CV_ + cv;

    const float4 pa = x[in_idx];                 // (2h,   2w)
    const float4 pb = x[in_idx + CV_];           // (2h,   2w+1)
    const float4 pc = x[in_idx + ROWV_];         // (2h+1, 2w)
    const float4 pd = x[in_idx + ROWV_ + CV_];   // (2h+1, 2w+1)

    float4 ll, lh, hl, hh;
#define DO_COMP(f)                                              \
    ll.f = 0.5f * ((pa.f + pb.f) + (pc.f + pd.f));              \
    lh.f = 0.5f * ((pb.f - pa.f) + (pd.f - pc.f));              \
    hl.f = 0.5f * ((pc.f + pd.f) - (pa.f + pb.f));              \
    hh.f = 0.5f * ((pa.f - pb.f) + (pd.f - pc.f));
    DO_COMP(x) DO_COMP(y) DO_COMP(z) DO_COMP(w)
#undef DO_COMP

    out[idx]             = ll;
    out[idx + SUBV_]     = lh;
    out[idx + 2 * SUBV_] = hl;
    out[idx + 3 * SUBV_] = hh;
}

extern "C" void kernel_launch(void* const* d_in, const int* in_sizes, int n_in,
                              void* d_out, int out_size, void* d_ws, size_t ws_size,
                              hipStream_t stream) {
    const float4* x = (const float4*)d_in[0];
    float4* out = (float4*)d_out;
    const int total = in_sizes[0] / 16;  // float4 elements per subband (= SUBV_)
    const int block = 256;
    const int grid = (total + block - 1) / block;
    WaveLetPooling_38843684225881_kernel<<<grid, block, 0, stream>>>(x, out, total);
}

// Round 2
// 202.897 us; speedup vs baseline: 1.0056x; 1.0056x over previous
//
#include <hip/hip_runtime.h>

// Problem shape (fixed by setup_inputs): x = (B=8, H=512, W=512, C=64) fp32, NHWC.
// Outputs: ll, lh, hl, hh each (8, 256, 256, 64) fp32, concatenated in d_out.

#define B_    8
#define H_    512
#define W_    512
#define C_    64
#define HO_   (H_ / 2)
#define WO_   (W_ / 2)
#define CV_   (C_ / 4)                       // float4 chunks per pixel = 16
#define ROWV_ (W_ * CV_)                     // input row stride in float4 = 8192
#define SUBV_ (B_ * HO_ * WO_ * CV_)         // one subband, in float4 = 8388608

typedef float f32x4 __attribute__((ext_vector_type(4)));

__global__ __launch_bounds__(256) void WaveLetPooling_38843684225881_kernel(
    const f32x4* __restrict__ x, f32x4* __restrict__ out, int total)
{
    int idx = blockIdx.x * blockDim.x + threadIdx.x;
    if (idx >= total) return;

    // idx = ((b*HO + h)*WO + w)*CV + cv   (CV=16, WO=256, HO=256 are powers of 2)
    const int cv = idx & (CV_ - 1);
    const int w  = (idx >> 4) & (WO_ - 1);
    const int h  = (idx >> 12) & (HO_ - 1);
    const int b  = idx >> 20;

    // input float4 index of (b, 2h, 2w, 4*cv)
    const int in_idx = ((b * H_ + 2 * h) * W_ + 2 * w) * CV_ + cv;

    // Streaming access: every line touched exactly once -> bypass cache retention.
    const f32x4 pa = __builtin_nontemporal_load(&x[in_idx]);                // (2h,   2w)
    const f32x4 pb = __builtin_nontemporal_load(&x[in_idx + CV_]);          // (2h,   2w+1)
    const f32x4 pc = __builtin_nontemporal_load(&x[in_idx + ROWV_]);        // (2h+1, 2w)
    const f32x4 pd = __builtin_nontemporal_load(&x[in_idx + ROWV_ + CV_]);  // (2h+1, 2w+1)

    const f32x4 sab = pa + pb;
    const f32x4 scd = pc + pd;
    const f32x4 ll = 0.5f * (sab + scd);
    const f32x4 lh = 0.5f * ((pb - pa) + (pd - pc));
    const f32x4 hl = 0.5f * (scd - sab);
    const f32x4 hh = 0.5f * ((pa - pb) + (pd - pc));

    __builtin_nontemporal_store(ll, &out[idx]);
    __builtin_nontemporal_store(lh, &out[idx + SUBV_]);
    __builtin_nontemporal_store(hl, &out[idx + 2 * SUBV_]);
    __builtin_nontemporal_store(hh, &out[idx + 3 * SUBV_]);
}

extern "C" void kernel_launch(void* const* d_in, const int* in_sizes, int n_in,
                              void* d_out, int out_size, void* d_ws, size_t ws_size,
                              hipStream_t stream) {
    const f32x4* x = (const f32x4*)d_in[0];
    f32x4* out = (f32x4*)d_out;
    const int total = in_sizes[0] / 16;  // float4 elements per subband (= SUBV_)
    const int block = 256;
    const int grid = (total + block - 1) / block;
    WaveLetPooling_38843684225881_kernel<<<grid, block, 0, stream>>>(x, out, total);
}

// Round 3
// 184.086 us; speedup vs baseline: 1.1084x; 1.1022x over previous
//
#include <hip/hip_runtime.h>

// Problem shape (fixed by setup_inputs): x = (B=8, H=512, W=512, C=64) fp32, NHWC.
// Outputs: ll, lh, hl, hh each (8, 256, 256, 64) fp32, concatenated in d_out.

#define B_    8
#define H_    512
#define W_    512
#define C_    64
#define HO_   (H_ / 2)
#define WO_   (W_ / 2)
#define CV_   (C_ / 4)                       // float4 chunks per pixel = 16
#define ROWV_ (W_ * CV_)                     // input row stride in float4 = 8192
#define SUBV_ (B_ * HO_ * WO_ * CV_)         // one subband, in float4 = 8388608
#define HALFV_ (SUBV_ / 2)                   // chunks per half (batches 0-3 / 4-7)
#define INHALF_ (4 * H_ * ROWV_)             // input chunks per 4 batches

typedef float f32x4 __attribute__((ext_vector_type(4)));

__device__ __forceinline__ void haar4(const f32x4 pa, const f32x4 pb,
                                      const f32x4 pc, const f32x4 pd,
                                      f32x4& ll, f32x4& lh, f32x4& hl, f32x4& hh)
{
    const f32x4 sab = pa + pb;
    const f32x4 scd = pc + pd;
    ll = 0.5f * (sab + scd);
    lh = 0.5f * ((pb - pa) + (pd - pc));
    hl = 0.5f * (scd - sab);
    hh = 0.5f * ((pa - pb) + (pd - pc));
}

__global__ __launch_bounds__(256) void WaveLetPooling_38843684225881_kernel(
    const f32x4* __restrict__ x, f32x4* __restrict__ out)
{
    const int idx = blockIdx.x * blockDim.x + threadIdx.x;  // [0, HALFV_)

    // idx = ((b*HO + h)*WO + w)*CV + cv ; second position = same (h,w,cv), b+4
    const int cv = idx & (CV_ - 1);
    const int w  = (idx >> 4) & (WO_ - 1);
    const int h  = (idx >> 12) & (HO_ - 1);
    const int b  = idx >> 20;

    const int in_idx = ((b * H_ + 2 * h) * W_ + 2 * w) * CV_ + cv;

    // Two independent positions -> 8 loads in flight per thread.
    const f32x4 pa0 = __builtin_nontemporal_load(&x[in_idx]);
    const f32x4 pb0 = __builtin_nontemporal_load(&x[in_idx + CV_]);
    const f32x4 pc0 = __builtin_nontemporal_load(&x[in_idx + ROWV_]);
    const f32x4 pd0 = __builtin_nontemporal_load(&x[in_idx + ROWV_ + CV_]);
    const f32x4 pa1 = __builtin_nontemporal_load(&x[in_idx + INHALF_]);
    const f32x4 pb1 = __builtin_nontemporal_load(&x[in_idx + INHALF_ + CV_]);
    const f32x4 pc1 = __builtin_nontemporal_load(&x[in_idx + INHALF_ + ROWV_]);
    const f32x4 pd1 = __builtin_nontemporal_load(&x[in_idx + INHALF_ + ROWV_ + CV_]);

    f32x4 ll0, lh0, hl0, hh0, ll1, lh1, hl1, hh1;
    haar4(pa0, pb0, pc0, pd0, ll0, lh0, hl0, hh0);
    haar4(pa1, pb1, pc1, pd1, ll1, lh1, hl1, hh1);

    __builtin_nontemporal_store(ll0, &out[idx]);
    __builtin_nontemporal_store(lh0, &out[idx + SUBV_]);
    __builtin_nontemporal_store(hl0, &out[idx + 2 * SUBV_]);
    __builtin_nontemporal_store(hh0, &out[idx + 3 * SUBV_]);
    __builtin_nontemporal_store(ll1, &out[idx + HALFV_]);
    __builtin_nontemporal_store(lh1, &out[idx + HALFV_ + SUBV_]);
    __builtin_nontemporal_store(hl1, &out[idx + HALFV_ + 2 * SUBV_]);
    __builtin_nontemporal_store(hh1, &out[idx + HALFV_ + 3 * SUBV_]);
}

extern "C" void kernel_launch(void* const* d_in, const int* in_sizes, int n_in,
                              void* d_out, int out_size, void* d_ws, size_t ws_size,
                              hipStream_t stream) {
    const f32x4* x = (const f32x4*)d_in[0];
    f32x4* out = (f32x4*)d_out;
    const int threads_total = HALFV_;        // each thread does 2 positions
    const int block = 256;
    const int grid = threads_total / block;  // 16384
    WaveLetPooling_38843684225881_kernel<<<grid, block, 0, stream>>>(x, out);
}